// Round 8
// baseline (346.765 us; speedup 1.0000x reference)
//
#include <hip/hip_runtime.h>
#include <hip/hip_bf16.h>
#include <math.h>

#define B_   16
#define N_   1024
#define H_   4
#define D240 240
#define SC_  57600   // 240*240

typedef unsigned short ushort;
typedef __attribute__((ext_vector_type(8))) short bf16x8;
typedef __attribute__((ext_vector_type(8))) unsigned short u16x8;
typedef __attribute__((ext_vector_type(4))) float f32x4;

__device__ __forceinline__ ushort f2b(float v) {
  __hip_bfloat16 h = __float2bfloat16(v);
  return *reinterpret_cast<ushort*>(&h);
}

__device__ __forceinline__ void gload16(const void* g, void* s) {
  __builtin_amdgcn_global_load_lds((const __attribute__((address_space(1))) void*)g,
                                   (__attribute__((address_space(3))) void*)s, 16, 0, 0);
}

__device__ __forceinline__ u16x8 cvt8(float4 a, float4 b) {
  u16x8 w;
  w[0] = f2b(a.x); w[1] = f2b(a.y); w[2] = f2b(a.z); w[3] = f2b(a.w);
  w[4] = f2b(b.x); w[5] = f2b(b.y); w[6] = f2b(b.z); w[7] = f2b(b.w);
  return w;
}

// ---------------------------------------------------------------------------
// conv_weights: Wk_b | Wv_b | Wq_bd (block-diag per head) | Wo_b (col-permuted)
// ---------------------------------------------------------------------------
__global__ __launch_bounds__(256) void conv_weights(
    const float* __restrict__ Wk, const float* __restrict__ Wv,
    const float* __restrict__ q1, const float* __restrict__ q2,
    const float* __restrict__ q3, const float* __restrict__ q4,
    const float* __restrict__ o1, const float* __restrict__ o2,
    const float* __restrict__ o3, const float* __restrict__ o4,
    ushort* __restrict__ wts) {
  long i = (long)blockIdx.x * 256 + threadIdx.x;
  if (i >= 716800) return;
  float v = 0.f;
  if (i < 122880) {
    const float* src = (i < 61440) ? Wk : Wv;
    long j = (i < 61440) ? i : i - 61440;
    int r = j / 256, k = j % 256;
    if (k < 240) v = src[(long)r * 240 + k];
  } else if (i < 368640) {
    long j = i - 122880;
    int h = j / 61440; int rem = j % 61440;
    int r = rem / 256, k = rem % 256;
    int s = r < 16 ? 0 : r < 48 ? 1 : r < 112 ? 2 : 3;
    const int dss[4] = {16, 32, 64, 128};
    const int qf[4]  = {0, 16, 48, 112};
    const float* qs[4] = {q1, q2, q3, q4};
    int d = dss[s], off = qf[s];
    if (k >= off && k < off + d)
      v = qs[s][((long)(h * d + (r - off))) * d + (k - off)];
  } else {
    long j = i - 368640;
    int s = j < 4096 ? 0 : j < 20480 ? 1 : j < 86016 ? 2 : 3;
    const long base[4] = {0, 4096, 20480, 86016};
    const int cs[4] = {64, 128, 256, 512};
    const float* os[4] = {o1, o2, o3, o4};
    long rem = j - base[s];
    int c = cs[s], d = c >> 2;
    int e = rem / c, kk = rem % c;
    v = os[s][(long)e * c + (kk % d) * 4 + kk / d];
  }
  wts[i] = f2b(v);
}

// ---------------------------------------------------------------------------
// mfma_proj (fused fp32 conversion): K/V/Q projections, 3072 blocks.
// One operand is a bf16 weight (gload16); the other is staged directly from
// the fp32 inputs (2x float4 load -> cvt -> ds_write_b128), with the next
// iteration's fp32 loads prefetched behind the MFMA phase. This replaces the
// conv_inputs pass entirely (heads_b / emb_h never materialized).
// [0,1024):    K: Kh_T[bh][e][n]  = sum_d Wk[e,d]*heads(emb_all)[bh,n,d]
// [1024,2048): V: Vh[bh][n][e]    = sum_d heads(emb_all)[bh,n,d]*Wv[e,d]
// [2048,3072): Q: Q_T[bh][r][n]   = sum_d Wq_bd[h][r,d]*emb_h(e1..4)[bh,n,d]
// ---------------------------------------------------------------------------
__global__ __launch_bounds__(256) void mfma_proj(
    const float* __restrict__ emb_all,
    const float* __restrict__ e1, const float* __restrict__ e2,
    const float* __restrict__ e3, const float* __restrict__ e4,
    const ushort* __restrict__ Wk_b, const ushort* __restrict__ Wv_b,
    const ushort* __restrict__ Wq_bd,
    ushort* __restrict__ Kh_T, ushort* __restrict__ Vh, ushort* __restrict__ Q_T)
{
  __shared__ __align__(16) ushort As[128 * 32];
  __shared__ __align__(16) ushort Bs[128 * 32];

  const int bx = blockIdx.x;
  const int mode = bx < 1024 ? 0 : bx < 2048 ? 1 : 2;   // 0=K,1=V,2=Q
  const int local = bx - (mode == 0 ? 0 : mode == 1 ? 1024 : 2048);
  const int bh = local >> 4, t16 = local & 15;
  const int b = bh >> 2, h = bh & 3;

  int m0, n0;
  const ushort* W;
  ushort* C; long ldc; int M, Nn, Npad;
  if (mode == 0) {
    m0 = (t16 >> 3) * 128; n0 = (t16 & 7) * 128;
    W = Wk_b; C = Kh_T + (long)bh * 240 * 1024; ldc = 1024;
    M = 240; Nn = 1024; Npad = 1024;
  } else if (mode == 1) {
    m0 = (t16 >> 1) * 128; n0 = (t16 & 1) * 128;
    W = Wv_b; C = Vh + (long)bh * 1024 * 256; ldc = 256;
    M = 1024; Nn = 240; Npad = 256;
  } else {
    m0 = (t16 >> 3) * 128; n0 = (t16 & 7) * 128;
    W = Wq_bd + h * 61440; C = Q_T + (long)bh * 240 * 1024; ldc = 1024;
    M = 240; Nn = 1024; Npad = 1024;
  }
  const bool wa = (mode != 1);          // weight-is-A
  const int wbase = wa ? m0 : n0;       // weight tile rows (dim of size 240)
  const int cbase = wa ? n0 : m0;       // converted tile rows (n, always <1024)

  const int tid = threadIdx.x;
  const int l = tid & 63, w = tid >> 6;
  const int wy = w >> 1, wx = w & 1;
  const int srow = tid >> 2;
  const int skc  = (tid & 3) * 8;

  // weight staging (gload16), rows clamped to 239
  int wr0 = wbase + srow;      wr0 = wr0 < 240 ? wr0 : 239;
  int wr1 = wbase + srow + 64; wr1 = wr1 < 240 ? wr1 : 239;
  const ushort* w0p = W + (long)wr0 * 256 + skc;
  const ushort* w1p = W + (long)wr1 * 256 + skc;
  ushort* Ws = wa ? As : Bs;
  ushort* Cs = wa ? Bs : As;
  ushort* lW0 = Ws + srow * 32 + skc;
  ushort* lW1 = Ws + (srow + 64) * 32 + skc;
  ushort* lC0 = Cs + srow * 32 + skc;
  ushort* lC1 = Cs + (srow + 64) * 32 + skc;

  // converted-operand row bases (fp32 sources)
  const long rowb0 = (long)(b * 1024 + cbase + srow);
  const long rowb1 = rowb0 + 64;

  // fp32 load for channel group starting at k (8 channels)
  auto ldconv = [&](int k, float4 f[4]) {
    f[0] = f[1] = f[2] = f[3] = make_float4(0.f, 0.f, 0.f, 0.f);
    if (k < 240) {
      const float* base; long str, off;
      if (mode == 2) {
        if (k < 16)       { base = e1; str = 64;  off = h * 16  + k; }
        else if (k < 48)  { base = e2; str = 128; off = h * 32  + (k - 16); }
        else if (k < 112) { base = e3; str = 256; off = h * 64  + (k - 48); }
        else              { base = e4; str = 512; off = h * 128 + (k - 112); }
      } else {
        base = emb_all; str = 960;
        if (k < 16)       off = h * 16 + k;
        else if (k < 48)  off = 64  + h * 32  + (k - 16);
        else if (k < 112) off = 192 + h * 64  + (k - 48);
        else              off = 448 + h * 128 + (k - 112);
      }
      const float* s0 = base + rowb0 * str + off;
      const float* s1 = base + rowb1 * str + off;
      f[0] = *(const float4*)s0; f[1] = *(const float4*)(s0 + 4);
      f[2] = *(const float4*)s1; f[3] = *(const float4*)(s1 + 4);
    }
  };

  f32x4 acc[4][4];
  #pragma unroll
  for (int i = 0; i < 4; ++i)
    #pragma unroll
    for (int j = 0; j < 4; ++j) acc[i][j] = (f32x4)0.f;

  const ushort* arp = As + (wy * 64 + (l & 15)) * 32 + (l >> 4) * 8;
  const ushort* brp = Bs + (wx * 64 + (l & 15)) * 32 + (l >> 4) * 8;

  float4 f[4];
  ldconv(skc, f);                      // prologue: k0 = 0

  for (int k0 = 0; k0 < 256; k0 += 32) {
    __syncthreads();
    gload16(w0p + k0, lW0);
    gload16(w1p + k0, lW1);
    *(u16x8*)lC0 = cvt8(f[0], f[1]);
    *(u16x8*)lC1 = cvt8(f[2], f[3]);
    if (k0 + 32 < 256) ldconv(k0 + 32 + skc, f);   // prefetch behind MFMA phase
    __syncthreads();
    bf16x8 af[4], bfr[4];
    #pragma unroll
    for (int i = 0; i < 4; ++i) af[i]  = *(const bf16x8*)(arp + i * 512);
    #pragma unroll
    for (int j = 0; j < 4; ++j) bfr[j] = *(const bf16x8*)(brp + j * 512);
    #pragma unroll
    for (int i = 0; i < 4; ++i)
      #pragma unroll
      for (int j = 0; j < 4; ++j)
        acc[i][j] = __builtin_amdgcn_mfma_f32_16x16x32_bf16(af[i], bfr[j], acc[i][j], 0, 0, 0);
  }

  const int quad = l >> 4, lc = l & 15;
  #pragma unroll
  for (int i = 0; i < 4; ++i) {
    #pragma unroll
    for (int r = 0; r < 4; ++r) {
      int row = m0 + wy * 64 + i * 16 + quad * 4 + r;
      if (row >= M) continue;
      ushort* Cr = C + (long)row * ldc;
      #pragma unroll
      for (int j = 0; j < 4; ++j) {
        int col = n0 + wx * 64 + j * 16 + lc;
        if (col < Nn) Cr[col] = f2b(acc[i][j][r]);
        else if (col < Npad) Cr[col] = 0;
      }
    }
  }
}

// ---------------------------------------------------------------------------
// MFMA GEMM (generic, fp32/bf16 out) — used for scores (split-K via grid.z).
// ---------------------------------------------------------------------------
__global__ __launch_bounds__(256) void mfma_abT(
    const ushort* __restrict__ A, long lda, long AsY, long AsZ,
    const ushort* __restrict__ Bm, long ldb, long BsY, long BsZ,
    void* __restrict__ Cv, long ldc, long CsY, long CsZ,
    int M, int Nn, int Npad, int K, float alpha, int c_bf16, int tilesN)
{
  A  += blockIdx.y * AsY + blockIdx.z * AsZ;
  Bm += blockIdx.y * BsY + blockIdx.z * BsZ;

  const int m0 = (blockIdx.x / tilesN) * 128;
  const int n0 = (blockIdx.x % tilesN) * 128;
  const int tid = threadIdx.x;
  const int l = tid & 63, w = tid >> 6;
  const int wy = w >> 1, wx = w & 1;

  __shared__ __align__(16) ushort As[128 * 32];
  __shared__ __align__(16) ushort Bs[128 * 32];

  f32x4 acc[4][4];
  #pragma unroll
  for (int i = 0; i < 4; ++i)
    #pragma unroll
    for (int j = 0; j < 4; ++j) acc[i][j] = (f32x4)0.f;

  const int srow = tid >> 2;
  const int skc  = (tid & 3) * 8;
  int ra0 = m0 + srow;      ra0 = ra0 < M  ? ra0 : M - 1;
  int ra1 = m0 + srow + 64; ra1 = ra1 < M  ? ra1 : M - 1;
  int rb0 = n0 + srow;      rb0 = rb0 < Nn ? rb0 : Nn - 1;
  int rb1 = n0 + srow + 64; rb1 = rb1 < Nn ? rb1 : Nn - 1;
  const ushort* a0 = A  + (long)ra0 * lda + skc;
  const ushort* a1 = A  + (long)ra1 * lda + skc;
  const ushort* b0 = Bm + (long)rb0 * ldb + skc;
  const ushort* b1 = Bm + (long)rb1 * ldb + skc;
  ushort* lA0 = As + srow * 32 + skc;
  ushort* lA1 = As + (srow + 64) * 32 + skc;
  ushort* lB0 = Bs + srow * 32 + skc;
  ushort* lB1 = Bs + (srow + 64) * 32 + skc;

  const ushort* arp = As + (wy * 64 + (l & 15)) * 32 + (l >> 4) * 8;
  const ushort* brp = Bs + (wx * 64 + (l & 15)) * 32 + (l >> 4) * 8;

  for (int k0 = 0; k0 < K; k0 += 32) {
    __syncthreads();
    gload16(a0 + k0, lA0);
    gload16(a1 + k0, lA1);
    gload16(b0 + k0, lB0);
    gload16(b1 + k0, lB1);
    __syncthreads();
    bf16x8 af[4], bfr[4];
    #pragma unroll
    for (int i = 0; i < 4; ++i) af[i]  = *(const bf16x8*)(arp + i * 512);
    #pragma unroll
    for (int j = 0; j < 4; ++j) bfr[j] = *(const bf16x8*)(brp + j * 512);
    #pragma unroll
    for (int i = 0; i < 4; ++i)
      #pragma unroll
      for (int j = 0; j < 4; ++j)
        acc[i][j] = __builtin_amdgcn_mfma_f32_16x16x32_bf16(af[i], bfr[j], acc[i][j], 0, 0, 0);
  }

  const int quad = l >> 4, lc = l & 15;
  if (c_bf16) {
    ushort* C = (ushort*)Cv + blockIdx.y * CsY + blockIdx.z * CsZ;
    #pragma unroll
    for (int i = 0; i < 4; ++i) {
      #pragma unroll
      for (int r = 0; r < 4; ++r) {
        int row = m0 + wy * 64 + i * 16 + quad * 4 + r;
        if (row >= M) continue;
        ushort* Cr = C + (long)row * ldc;
        #pragma unroll
        for (int j = 0; j < 4; ++j) {
          int col = n0 + wx * 64 + j * 16 + lc;
          if (col < Nn) Cr[col] = f2b(acc[i][j][r] * alpha);
          else if (col < Npad) Cr[col] = 0;
        }
      }
    }
  } else {
    float* C = (float*)Cv + blockIdx.y * CsY + blockIdx.z * CsZ;
    #pragma unroll
    for (int i = 0; i < 4; ++i) {
      #pragma unroll
      for (int r = 0; r < 4; ++r) {
        int row = m0 + wy * 64 + i * 16 + quad * 4 + r;
        if (row >= M) continue;
        float* Cr = C + (long)row * ldc;
        #pragma unroll
        for (int j = 0; j < 4; ++j) {
          int col = n0 + wx * 64 + j * 16 + lc;
          if (col < Nn) Cr[col] = acc[i][j][r] * alpha;
        }
      }
    }
  }
}

// ---------------------------------------------------------------------------
// mfma_ctx: fused ctx GEMM. A=Vh[bh] [1024,256], B=P_b[bh] [240,256], K=256.
// Epilogue maps col -> h-interleaved channel in ctx2 [B,N,960] bf16.
// ---------------------------------------------------------------------------
__global__ __launch_bounds__(256) void mfma_ctx(const ushort* __restrict__ V,
                                                const ushort* __restrict__ P,
                                                ushort* __restrict__ ctx2) {
  const int h = blockIdx.y, b = blockIdx.z;
  const ushort* A  = V + (((long)b * H_ + h) * 1024) * 256;
  const ushort* Bm = P + (((long)b * H_ + h) * 240) * 256;

  const int m0 = (blockIdx.x >> 1) * 128;
  const int n0 = (blockIdx.x & 1) * 128;
  const int tid = threadIdx.x;
  const int l = tid & 63, w = tid >> 6;
  const int wy = w >> 1, wx = w & 1;

  __shared__ __align__(16) ushort As[128 * 32];
  __shared__ __align__(16) ushort Bs[128 * 32];

  f32x4 acc[4][4];
  #pragma unroll
  for (int i = 0; i < 4; ++i)
    #pragma unroll
    for (int j = 0; j < 4; ++j) acc[i][j] = (f32x4)0.f;

  const int srow = tid >> 2;
  const int skc  = (tid & 3) * 8;
  int rb0 = n0 + srow;      rb0 = rb0 < 240 ? rb0 : 239;
  int rb1 = n0 + srow + 64; rb1 = rb1 < 240 ? rb1 : 239;
  const ushort* a0 = A  + (long)(m0 + srow) * 256 + skc;
  const ushort* a1 = A  + (long)(m0 + srow + 64) * 256 + skc;
  const ushort* b0 = Bm + (long)rb0 * 256 + skc;
  const ushort* b1 = Bm + (long)rb1 * 256 + skc;
  ushort* lA0 = As + srow * 32 + skc;
  ushort* lA1 = As + (srow + 64) * 32 + skc;
  ushort* lB0 = Bs + srow * 32 + skc;
  ushort* lB1 = Bs + (srow + 64) * 32 + skc;

  const ushort* arp = As + (wy * 64 + (l & 15)) * 32 + (l >> 4) * 8;
  const ushort* brp = Bs + (wx * 64 + (l & 15)) * 32 + (l >> 4) * 8;

  for (int k0 = 0; k0 < 256; k0 += 32) {
    __syncthreads();
    gload16(a0 + k0, lA0);
    gload16(a1 + k0, lA1);
    gload16(b0 + k0, lB0);
    gload16(b1 + k0, lB1);
    __syncthreads();
    bf16x8 af[4], bfr[4];
    #pragma unroll
    for (int i = 0; i < 4; ++i) af[i]  = *(const bf16x8*)(arp + i * 512);
    #pragma unroll
    for (int j = 0; j < 4; ++j) bfr[j] = *(const bf16x8*)(brp + j * 512);
    #pragma unroll
    for (int i = 0; i < 4; ++i)
      #pragma unroll
      for (int j = 0; j < 4; ++j)
        acc[i][j] = __builtin_amdgcn_mfma_f32_16x16x32_bf16(af[i], bfr[j], acc[i][j], 0, 0, 0);
  }

  const int quad = l >> 4, lc = l & 15;
  const int dss[4] = {16, 32, 64, 128};
  const int qf[4]  = {0, 16, 48, 112};
  const int cf[4]  = {0, 64, 192, 448};
  #pragma unroll
  for (int i = 0; i < 4; ++i) {
    #pragma unroll
    for (int r = 0; r < 4; ++r) {
      int row = m0 + wy * 64 + i * 16 + quad * 4 + r;
      ushort* Cr = ctx2 + ((long)b * N_ + row) * 960;
      #pragma unroll
      for (int j = 0; j < 4; ++j) {
        int col = n0 + wx * 64 + j * 16 + lc;
        if (col < 240) {
          int s = col < 16 ? 0 : col < 48 ? 1 : col < 112 ? 2 : 3;
          int chan = cf[s] + h * dss[s] + (col - qf[s]);
          Cr[chan] = f2b(acc[i][j][r]);
        }
      }
    }
  }
}

// ---------------------------------------------------------------------------
// mfma_oproj: grouped out-projection, one dispatch for all 4 scales.
// ---------------------------------------------------------------------------
__global__ __launch_bounds__(256) void mfma_oproj(const ushort* __restrict__ ctx2,
                                                  const ushort* __restrict__ Wo_b,
                                                  float* __restrict__ out) {
  const int bx = blockIdx.x;
  int s = bx < 128 ? 0 : bx < 256 ? 1 : bx < 512 ? 2 : 3;
  const int sbase[4] = {0, 128, 256, 512};
  const int cs_[4]   = {64, 128, 256, 512};
  const int coff_[4] = {0, 64, 192, 448};
  const int wo_[4]   = {0, 4096, 20480, 86016};
  const long oo_[4]  = {0, 1048576, 3145728, 7340032};
  const int c = cs_[s];
  const int nt = (c + 127) >> 7;
  const int local = bx - sbase[s];
  const int m0 = (local / nt) * 128;
  const int n0 = (local % nt) * 128;

  const ushort* A  = ctx2 + coff_[s];
  const ushort* Bm = Wo_b + wo_[s];
  float* C = out + oo_[s];
  const int K = c, Nn = c;

  const int tid = threadIdx.x;
  const int l = tid & 63, w = tid >> 6;
  const int wy = w >> 1, wx = w & 1;

  __shared__ __align__(16) ushort As[128 * 32];
  __shared__ __align__(16) ushort Bs[128 * 32];

  f32x4 acc[4][4];
  #pragma unroll
  for (int i = 0; i < 4; ++i)
    #pragma unroll
    for (int j = 0; j < 4; ++j) acc[i][j] = (f32x4)0.f;

  const int srow = tid >> 2;
  const int skc  = (tid & 3) * 8;
  int rb0 = n0 + srow;      rb0 = rb0 < Nn ? rb0 : Nn - 1;
  int rb1 = n0 + srow + 64; rb1 = rb1 < Nn ? rb1 : Nn - 1;
  const ushort* a0 = A  + (long)(m0 + srow) * 960 + skc;
  const ushort* a1 = A  + (long)(m0 + srow + 64) * 960 + skc;
  const ushort* b0 = Bm + (long)rb0 * c + skc;
  const ushort* b1 = Bm + (long)rb1 * c + skc;
  ushort* lA0 = As + srow * 32 + skc;
  ushort* lA1 = As + (srow + 64) * 32 + skc;
  ushort* lB0 = Bs + srow * 32 + skc;
  ushort* lB1 = Bs + (srow + 64) * 32 + skc;

  const ushort* arp = As + (wy * 64 + (l & 15)) * 32 + (l >> 4) * 8;
  const ushort* brp = Bs + (wx * 64 + (l & 15)) * 32 + (l >> 4) * 8;

  for (int k0 = 0; k0 < K; k0 += 32) {
    __syncthreads();
    gload16(a0 + k0, lA0);
    gload16(a1 + k0, lA1);
    gload16(b0 + k0, lB0);
    gload16(b1 + k0, lB1);
    __syncthreads();
    bf16x8 af[4], bfr[4];
    #pragma unroll
    for (int i = 0; i < 4; ++i) af[i]  = *(const bf16x8*)(arp + i * 512);
    #pragma unroll
    for (int j = 0; j < 4; ++j) bfr[j] = *(const bf16x8*)(brp + j * 512);
    #pragma unroll
    for (int i = 0; i < 4; ++i)
      #pragma unroll
      for (int j = 0; j < 4; ++j)
        acc[i][j] = __builtin_amdgcn_mfma_f32_16x16x32_bf16(af[i], bfr[j], acc[i][j], 0, 0, 0);
  }

  const int quad = l >> 4, lc = l & 15;
  #pragma unroll
  for (int i = 0; i < 4; ++i) {
    #pragma unroll
    for (int r = 0; r < 4; ++r) {
      int row = m0 + wy * 64 + i * 16 + quad * 4 + r;
      float* Cr = C + (long)row * c;
      #pragma unroll
      for (int j = 0; j < 4; ++j) {
        int col = n0 + wx * 64 + j * 16 + lc;
        if (col < Nn) Cr[col] = acc[i][j][r];
      }
    }
  }
}

// ---------------------------------------------------------------------------
// in_stats: per (bh, scale) mean/rstd over d*240 slice; sums split-K partials.
// ---------------------------------------------------------------------------
__global__ __launch_bounds__(256) void in_stats(const float* __restrict__ sc0,
                                                const float* __restrict__ sc1,
                                                float* __restrict__ stats) {
  const int doffs[4] = {0, 16, 48, 112};
  const int dss[4]   = {16, 32, 64, 128};
  const int bh = blockIdx.x, sidx = blockIdx.y;
  const long base = (long)bh * SC_ + doffs[sidx] * D240;
  const float4* A4 = (const float4*)(sc0 + base);
  const float4* B4 = (const float4*)(sc1 + base);
  const int n4 = dss[sidx] * 60;

  float s = 0.f, s2 = 0.f;
  for (int i = threadIdx.x; i < n4; i += 256) {
    float4 a = A4[i], b = B4[i];
    float x0 = a.x + b.x, x1 = a.y + b.y, x2 = a.z + b.z, x3 = a.w + b.w;
    s  += x0 + x1 + x2 + x3;
    s2 += x0 * x0 + x1 * x1 + x2 * x2 + x3 * x3;
  }
  #pragma unroll
  for (int o = 32; o > 0; o >>= 1) { s += __shfl_down(s, o); s2 += __shfl_down(s2, o); }

  __shared__ float wsum[4], wsum2[4];
  const int wave = threadIdx.x >> 6, lane = threadIdx.x & 63;
  if (lane == 0) { wsum[wave] = s; wsum2[wave] = s2; }
  __syncthreads();
  if (threadIdx.x == 0) {
    float n = (float)(n4 * 4);
    float ts = wsum[0] + wsum[1] + wsum[2] + wsum[3];
    float ts2 = wsum2[0] + wsum2[1] + wsum2[2] + wsum2[3];
    float mean = ts / n;
    float var = ts2 / n - mean * mean;
    stats[(bh * 4 + sidx) * 2]     = mean;
    stats[(bh * 4 + sidx) * 2 + 1] = rsqrtf(var + 1e-5f);
  }
}

// ---------------------------------------------------------------------------
// sm_apply: one wave per row; sums split-K partials, normalize + softmax -> P.
// ---------------------------------------------------------------------------
__global__ __launch_bounds__(256) void sm_apply(const float* __restrict__ sc0,
                                                const float* __restrict__ sc1,
                                                const float* __restrict__ stats,
                                                ushort* __restrict__ P) {
  const int bh = blockIdx.y;
  const int row = blockIdx.x * 4 + (threadIdx.x >> 6);
  const int lane = threadIdx.x & 63;
  const int s = row < 16 ? 0 : row < 48 ? 1 : row < 112 ? 2 : 3;
  const float mean = stats[(bh * 4 + s) * 2];
  const float rstd = stats[(bh * 4 + s) * 2 + 1];
  const long base = (long)bh * SC_ + (long)row * D240;
  const float* r0 = sc0 + base;
  const float* r1 = sc1 + base;
  ushort* p = P + ((long)bh * D240 + row) * 256;

  float v[4];
  float mx = -1e30f;
  #pragma unroll
  for (int j = 0; j < 4; ++j) {
    int c = lane + j * 64;
    v[j] = (c < D240) ? (r0[c] + r1[c] - mean) * rstd : -1e30f;
    mx = fmaxf(mx, v[j]);
  }
  #pragma unroll
  for (int o = 32; o > 0; o >>= 1) mx = fmaxf(mx, __shfl_xor(mx, o));
  float sum = 0.f;
  #pragma unroll
  for (int j = 0; j < 4; ++j) {
    int c = lane + j * 64;
    v[j] = (c < D240) ? __expf(v[j] - mx) : 0.f;
    sum += v[j];
  }
  #pragma unroll
  for (int o = 32; o > 0; o >>= 1) sum += __shfl_xor(sum, o);
  float inv = 1.f / sum;
  #pragma unroll
  for (int j = 0; j < 4; ++j) {
    int c = lane + j * 64;
    p[c] = (c < D240) ? f2b(v[j] * inv) : (ushort)0;
  }
}

// ---------------------------------------------------------------------------
// launch
// ---------------------------------------------------------------------------
extern "C" void kernel_launch(void* const* d_in, const int* in_sizes, int n_in,
                              void* d_out, int out_size, void* d_ws, size_t ws_size,
                              hipStream_t stream) {
  const float* emb[4] = {(const float*)d_in[0], (const float*)d_in[1],
                         (const float*)d_in[2], (const float*)d_in[3]};
  const float* emb_all = (const float*)d_in[4];
  const float* Wq[4] = {(const float*)d_in[5], (const float*)d_in[6],
                        (const float*)d_in[7], (const float*)d_in[8]};
  const float* Wk = (const float*)d_in[9];
  const float* Wv = (const float*)d_in[10];
  const float* Wo[4] = {(const float*)d_in[11], (const float*)d_in[12],
                        (const float*)d_in[13], (const float*)d_in[14]};
  float* out = (float*)d_out;
  float* sc0 = (float*)d_out;                  // split-K partial 0
  float* sc1 = (float*)d_out + 64L * SC_;      // split-K partial 1

  // ws layout (ushort offsets); heads_b/emb_h eliminated:
  ushort* wsb   = (ushort*)d_ws;
  ushort* P_b   = wsb;                 // [64,240,256]
  ushort* ctx2  = wsb + 4194304;       // [B,N,960]
  ushort* Q_T   = wsb + 33554432;      // [B,H,240,1024]
  ushort* Kh_T  = wsb + 49283072;      // [B,H,240,1024]
  ushort* Vh    = wsb + 65011712;      // [B,H,1024,256]
  ushort* wts   = wsb + 81788928;      // 716800: Wk_b|Wv_b|Wq_bd|Wo_b
  ushort* Wk_b  = wts;
  ushort* Wv_b  = wts + 61440;
  ushort* Wq_bd = wts + 122880;
  ushort* Wo_b  = wts + 368640;
  float*  stats = (float*)(wsb + 82505728);   // [64][4][2] fp32

  const float alpha_s = 1.0f / sqrtf(960.0f);

  conv_weights<<<dim3(2800), 256, 0, stream>>>(Wk, Wv, Wq[0], Wq[1], Wq[2], Wq[3],
                                               Wo[0], Wo[1], Wo[2], Wo[3], wts);

  // merged K/V/Q projections with fused fp32->bf16 staging (no conv_inputs pass)
  mfma_proj<<<dim3(3072), 256, 0, stream>>>(emb_all, emb[0], emb[1], emb[2], emb[3],
                                            Wk_b, Wv_b, Wq_bd, Kh_T, Vh, Q_T);

  // fused scores, split-K x2
  mfma_abT<<<dim3(4, 64, 2), 256, 0, stream>>>(
      Q_T, 1024, 240L * 1024, 512,
      Kh_T, 1024, 240L * 1024, 512,
      sc0, 240, (long)SC_, 64L * SC_,
      240, 240, 240, 512, alpha_s, 0, 2);

  // InstanceNorm stats + softmax apply (summing partials) -> bf16 probs
  in_stats<<<dim3(64, 4), 256, 0, stream>>>(sc0, sc1, stats);
  sm_apply<<<dim3(60, 64), 256, 0, stream>>>(sc0, sc1, stats, P_b);

  // fused ctx
  mfma_ctx<<<dim3(16, H_, B_), 256, 0, stream>>>(Vh, P_b, ctx2);

  // grouped out-proj
  mfma_oproj<<<dim3(1024), 256, 0, stream>>>(ctx2, Wo_b, out);
}